// Round 3
// baseline (1163.276 us; speedup 1.0000x reference)
//
#include <hip/hip_runtime.h>

// RGCN encoder: N=20000 nodes, E=640000 edges, F=64, H=128, L=2 layers,
// D=3 edge-attr dims, R=8 relations, block-diag B=4 blocks of c=32.
//
// R3: agg_kernel rebuilt as 1-wave (64-thread) blocks, float2 channels.
// Lane-parallel elist chunk load + __shfl distribution, 8-deep ping-pong
// gather pipeline (8 independent float2 gathers in flight while previous
// group's LDS accumulation runs). LDS s2[24][64] float2 accumulators
// (lane-owned channel pairs, no atomics), fused block-diag transform.

constexpr int H  = 128;
constexpr int F  = 64;
constexpr int D  = 3;
constexpr int R  = 8;
constexpr int B  = 4;
constexpr int C  = 32;
constexpr int ROWS = 8;     // gemm_h0
constexpr int ROWSB = 16;   // matB
constexpr int SCAN_CHUNK = 512;

// ---------------- CSR build (per-dst) ----------------

__global__ void count_edges(const int* __restrict__ ei, const int* __restrict__ attr,
                            int* __restrict__ cnt8, int E) {
  int e = blockIdx.x * 256 + threadIdx.x;
  if (e >= E) return;
  int dst = ei[E + e];
  #pragma unroll
  for (int j = 0; j < D; ++j) {
    int r = attr[e * D + j];
    atomicAdd(&cnt8[dst * (D * R) + j * R + r], 1);
  }
}

__global__ void indeg_from_cnt8(const int* __restrict__ cnt8, int* __restrict__ indeg, int N) {
  int n = blockIdx.x * 256 + threadIdx.x;
  if (n >= N) return;
  int s = 0;
  #pragma unroll
  for (int r = 0; r < R; ++r) s += cnt8[n * (D * R) + r];  // j=0 row counts each edge once
  indeg[n] = s;
}

__global__ void scan_a(const int* __restrict__ cnt, int* __restrict__ cexcl,
                       int* __restrict__ bsum, int nseg) {
  __shared__ int tmp[2][SCAN_CHUNK];
  int t = threadIdx.x;
  int gid = blockIdx.x * SCAN_CHUNK + t;
  int v = (gid < nseg) ? cnt[gid] : 0;
  int pa = 0;
  tmp[0][t] = v;
  __syncthreads();
  for (int off = 1; off < SCAN_CHUNK; off <<= 1) {
    tmp[1 - pa][t] = tmp[pa][t] + ((t >= off) ? tmp[pa][t - off] : 0);
    pa = 1 - pa;
    __syncthreads();
  }
  int incl = tmp[pa][t];
  if (gid < nseg) cexcl[gid] = incl - v;
  if (t == SCAN_CHUNK - 1) bsum[blockIdx.x] = incl;
}

__global__ void scan_b(int* __restrict__ bsum, int nblk) {
  __shared__ int tmp[2][1024];
  int t = threadIdx.x;
  int v = (t < nblk) ? bsum[t] : 0;
  int pa = 0;
  tmp[0][t] = v;
  __syncthreads();
  for (int off = 1; off < 1024; off <<= 1) {
    tmp[1 - pa][t] = tmp[pa][t] + ((t >= off) ? tmp[pa][t - off] : 0);
    pa = 1 - pa;
    __syncthreads();
  }
  if (t < nblk) bsum[t] = tmp[pa][t] - v;  // exclusive
}

__global__ void scan_c(const int* __restrict__ cexcl, const int* __restrict__ bsum,
                       int* __restrict__ offs, int nseg, int total) {
  int gid = blockIdx.x * 256 + threadIdx.x;
  if (gid < nseg) offs[gid] = cexcl[gid] + bsum[gid / SCAN_CHUNK];
  if (gid == 0) offs[nseg] = total;
}

__global__ void copy_int(const int* __restrict__ a, int* __restrict__ b, int n) {
  int i = blockIdx.x * 256 + threadIdx.x;
  if (i < n) b[i] = a[i];
}

__global__ void fill_edges(const int* __restrict__ ei, const int* __restrict__ attr,
                           int* __restrict__ cursor, unsigned* __restrict__ elist, int E) {
  int e = blockIdx.x * 256 + threadIdx.x;
  if (e >= E) return;
  int src = ei[e];
  int dst = ei[E + e];
  unsigned r0 = attr[e * D + 0], r1 = attr[e * D + 1], r2 = attr[e * D + 2];
  unsigned u = (unsigned)src | (r0 << 16) | (r1 << 20) | (r2 << 24);
  int p = atomicAdd(&cursor[dst], 1);
  elist[p] = u;
}

// ---------------- h0 = x @ emb ----------------

__global__ __launch_bounds__(128) void gemm_h0(const float* __restrict__ x,
                                               const float* __restrict__ emb,
                                               float* __restrict__ h0, int N) {
  __shared__ float xs[ROWS][F];
  int r0 = blockIdx.x * ROWS;
  for (int i = threadIdx.x; i < ROWS * F; i += 128)
    xs[i >> 6][i & 63] = x[(size_t)r0 * F + i];
  __syncthreads();
  int d = threadIdx.x;
  float acc[ROWS] = {};
  for (int k = 0; k < F; ++k) {
    float ev = emb[k * H + d];
    #pragma unroll
    for (int r = 0; r < ROWS; ++r) acc[r] = fmaf(xs[r][k], ev, acc[r]);
  }
  #pragma unroll
  for (int r = 0; r < ROWS; ++r) h0[(size_t)(r0 + r) * H + d] = acc[r];
}

// ---------------- aggregation + block-diag transform ----------------
// One wave (64 threads) per dst node; lane t owns channels (2t, 2t+1).

__global__ __launch_bounds__(64) void agg_kernel(
    const float* __restrict__ hsrc, const int* __restrict__ offs,
    const unsigned* __restrict__ elist, const int* __restrict__ cnt8,
    const float* __restrict__ Wall, float* __restrict__ m, int N) {
  const int n = blockIdx.x;
  const int t = threadIdx.x;            // 0..63
  __shared__ float2 s2[D * R][64];      // 12 KB; lane-owned channel pairs
  __shared__ float sinv[D * R];

  #pragma unroll
  for (int jr = 0; jr < D * R; ++jr) s2[jr][t] = make_float2(0.f, 0.f);
  if (t < D * R) {
    int c = cnt8[n * (D * R) + t];
    sinv[t] = (c > 0) ? 1.f / (float)c : 0.f;
  }

  const int beg = offs[n];
  const int deg = offs[n + 1] - beg;
  const float2* __restrict__ hsrc2 = (const float2*)hsrc;  // row stride 64

  for (int base = 0; base < deg; base += 64) {
    const int nc = min(64, deg - base);
    const unsigned ul = (base + t < deg) ? elist[beg + base + t] : 0u;
    const int ngrp = (nc + 7) >> 3;

    float2 va[8]; unsigned ua[8];
    float2 vb[8]; unsigned ub[8];

    auto LOADG = [&](int g, float2 (&v)[8], unsigned (&u)[8]) {
      #pragma unroll
      for (int i = 0; i < 8; ++i) {
        const int idx = g * 8 + i;                 // < 64 always
        const unsigned uu = __shfl(ul, idx);
        u[i] = uu;
        v[i] = (idx < nc) ? hsrc2[(size_t)(uu & 0xFFFFu) * 64 + t]
                          : make_float2(0.f, 0.f);
      }
    };
    auto PROC = [&](const float2 (&v)[8], const unsigned (&u)[8]) {
      #pragma unroll
      for (int i = 0; i < 8; ++i) {
        const unsigned uu = u[i];
        const float2 vv = v[i];
        const int r0 = (uu >> 16) & 7;
        const int r1 = 8 + ((uu >> 20) & 7);
        const int r2 = 16 + ((uu >> 24) & 7);
        float2 a = s2[r0][t]; a.x += vv.x; a.y += vv.y; s2[r0][t] = a;
        float2 b = s2[r1][t]; b.x += vv.x; b.y += vv.y; s2[r1][t] = b;
        float2 c = s2[r2][t]; c.x += vv.x; c.y += vv.y; s2[r2][t] = c;
      }
    };

    LOADG(0, va, ua);
    for (int g = 0; g < ngrp; g += 2) {
      if (g + 1 < ngrp) LOADG(g + 1, vb, ub);
      PROC(va, ua);
      if (g + 1 < ngrp) {
        if (g + 2 < ngrp) LOADG(g + 2, va, ua);
        PROC(vb, ub);
      }
    }
  }
  __syncthreads();  // single wave: cheap; ensures LDS visibility for cross-lane reads

  // transform: lane t -> channels (2t, 2t+1); quarter q, dd = output ch within block
  const int q = t >> 4;
  const int dd = (t & 15) * 2;
  #pragma unroll
  for (int j = 0; j < D; ++j) {
    float ax = 0.f, ay = 0.f;
    #pragma unroll
    for (int r = 0; r < R; ++r) {
      const int jr = j * R + r;
      const float* __restrict__ Wr = Wall + (((size_t)jr * B + q) * C) * C;
      const float* __restrict__ srow = (const float*)&s2[jr][0];  // 128 floats
      float tx = 0.f, ty = 0.f;
      #pragma unroll
      for (int c = 0; c < C; ++c) {
        const float sv = srow[q * C + c];
        const float2 wv = *(const float2*)&Wr[c * C + dd];
        tx = fmaf(sv, wv.x, tx);
        ty = fmaf(sv, wv.y, ty);
      }
      const float si = sinv[jr];
      ax = fmaf(tx, si, ax);
      ay = fmaf(ty, si, ay);
    }
    float2* __restrict__ mrow = (float2*)&m[((size_t)j * N + n) * H];
    mrow[t] = make_float2(ax, ay);
  }
}

// ---------------- dense root matmul + msg add + relu ----------------

__global__ __launch_bounds__(128) void matB(
    const float* __restrict__ h, const float* __restrict__ m,
    const float* __restrict__ rootall, const float* __restrict__ biasall,
    float* __restrict__ out, int N_all, int N) {
  const int j = blockIdx.y;
  const int row0 = blockIdx.x * ROWSB;
  const int d = threadIdx.x;
  const float* root = rootall + (size_t)j * H * H;
  __shared__ float hs[ROWSB][H];

  #pragma unroll
  for (int r = 0; r < ROWSB; ++r)
    hs[r][d] = h[(size_t)(row0 + r) * H + d];
  __syncthreads();

  const float bias = biasall[j * H + d];
  float acc[ROWSB];
  #pragma unroll
  for (int r = 0; r < ROWSB; ++r) acc[r] = bias;

  for (int k = 0; k < H; ++k) {
    float rk = root[(size_t)k * H + d];
    #pragma unroll
    for (int r = 0; r < ROWSB; ++r) acc[r] = fmaf(hs[r][k], rk, acc[r]);
  }

  if (row0 + ROWSB <= N) {
    #pragma unroll
    for (int r = 0; r < ROWSB; ++r)
      acc[r] += m[((size_t)j * N + row0 + r) * H + d];
  }

  #pragma unroll
  for (int r = 0; r < ROWSB; ++r)
    out[((size_t)j * N_all + row0 + r) * H + d] = fmaxf(acc[r], 0.f);
}

// ---------------- launch ----------------

extern "C" void kernel_launch(void* const* d_in, const int* in_sizes, int n_in,
                              void* d_out, int out_size, void* d_ws, size_t ws_size,
                              hipStream_t stream) {
  const float* x    = (const float*)d_in[0];
  const int*   ei   = (const int*)d_in[1];
  const int*   attr = (const int*)d_in[2];
  const float* emb  = (const float*)d_in[3];
  const float* cw   = (const float*)d_in[4];
  const float* cr   = (const float*)d_in[5];
  const float* cb   = (const float*)d_in[6];
  float* out = (float*)d_out;

  const int N = in_sizes[0] / F;   // 20000
  const int E = in_sizes[1] / 2;   // 640000

  char* ws = (char*)d_ws;
  size_t woff = 0;
  auto alloc = [&](size_t bytes) -> void* {
    void* p = ws + woff;
    woff = (woff + bytes + 255) & ~(size_t)255;
    return p;
  };
  float*    h0     = (float*)alloc((size_t)N * H * 4);
  float*    h1     = (float*)alloc((size_t)D * N * H * 4);
  float*    m      = (float*)alloc((size_t)D * N * H * 4);
  int*      indeg  = (int*)alloc((size_t)N * 4);
  int*      cnt8   = (int*)alloc((size_t)N * D * R * 4);
  int*      cexcl  = (int*)alloc((size_t)N * 4);
  int*      bsum   = (int*)alloc(4096);
  int*      offs   = (int*)alloc((size_t)(N + 1) * 4);
  int*      cursor = (int*)alloc((size_t)N * 4);
  unsigned* elist  = (unsigned*)alloc((size_t)E * 4);

  hipMemsetAsync(cnt8, 0, (size_t)N * D * R * 4, stream);
  count_edges<<<(E + 255) / 256, 256, 0, stream>>>(ei, attr, cnt8, E);
  indeg_from_cnt8<<<(N + 255) / 256, 256, 0, stream>>>(cnt8, indeg, N);

  int nch = (N + SCAN_CHUNK - 1) / SCAN_CHUNK;  // 40
  scan_a<<<nch, SCAN_CHUNK, 0, stream>>>(indeg, cexcl, bsum, N);
  scan_b<<<1, 1024, 0, stream>>>(bsum, nch);
  scan_c<<<(N + 255) / 256, 256, 0, stream>>>(cexcl, bsum, offs, N, E);
  copy_int<<<(N + 255) / 256, 256, 0, stream>>>(offs, cursor, N);
  fill_edges<<<(E + 255) / 256, 256, 0, stream>>>(ei, attr, cursor, elist, E);

  gemm_h0<<<N / ROWS, 128, 0, stream>>>(x, emb, h0, N);

  // layer 0
  agg_kernel<<<N, 64, 0, stream>>>(h0, offs, elist, cnt8, cw, m, N);
  {
    dim3 grid(N / ROWSB, D);
    matB<<<grid, 128, 0, stream>>>(h0, m, cr, cb, h1, N, N);
  }
  // layer 1 (gathers only rows < N of h1)
  agg_kernel<<<N, 64, 0, stream>>>(h1, offs, elist, cnt8,
                                   cw + (size_t)D * R * B * C * C, m, N);
  {
    dim3 grid((D * N) / ROWSB, D);
    matB<<<grid, 128, 0, stream>>>(h1, m,
                                   cr + (size_t)D * H * H,
                                   cb + (size_t)D * H,
                                   out, D * N, N);
  }
}